// Round 2
// baseline (849.064 us; speedup 1.0000x reference)
//
#include <hip/hip_runtime.h>
#include <hip/hip_bf16.h>

#define HH 8
#define SS 128
#define CC 256
#define DD 32
#define NTOK 32768
#define NHB 2048
#define BNEPS 1e-5f

using bf16 = __hip_bfloat16;
typedef float f32x4 __attribute__((ext_vector_type(4)));
typedef __bf16 bf16x8 __attribute__((ext_vector_type(8)));

__device__ __forceinline__ bf16x8 ld8(const bf16* p) {
    return *reinterpret_cast<const bf16x8*>(p);
}

// ---------------- fp32 -> bf16 weight conversion (all 6 weights, 1 launch) ----------------
__global__ void cvt6(const float* __restrict__ wq, const float* __restrict__ wk,
                     const float* __restrict__ wv, const float* __restrict__ wo,
                     const float* __restrict__ w0, const float* __restrict__ w1,
                     bf16* __restrict__ out) {
    int i = (blockIdx.x * 256 + threadIdx.x) * 4;  // 0..524284
    const float* src;
    int off;
    if (i < 65536) { src = wq; off = i; }
    else if (i < 131072) { src = wk; off = i - 65536; }
    else if (i < 196608) { src = wv; off = i - 131072; }
    else if (i < 262144) { src = wo; off = i - 196608; }
    else if (i < 393216) { src = w0; off = i - 262144; }
    else { src = w1; off = i - 393216; }
#pragma unroll
    for (int u = 0; u < 4; u++) out[i + u] = __float2bfloat16(src[off + u]);
}

// ---------------- BN stats: per-channel sum / sumsq over rows ----------------
template <typename T>
__global__ void stats_kernel(const T* __restrict__ X, int ch, int rpb,
                             float* __restrict__ sum, float* __restrict__ sumsq) {
    int c = blockIdx.x * blockDim.x + threadIdx.x;
    size_t r0 = (size_t)blockIdx.y * rpb;
    float s = 0.f, s2 = 0.f;
    for (int i = 0; i < rpb; i++) {
        float v = (float)X[(r0 + i) * (size_t)ch + c];
        s += v; s2 += v * v;
    }
    atomicAdd(&sum[c], s);
    atomicAdd(&sumsq[c], s2);
}

// ---------------- BN apply (+optional ReLU) -> bf16, 8 elems/thread ----------------
template <typename T, bool RELU>
__global__ void bn_apply(const T* __restrict__ X, bf16* __restrict__ out,
                         const float* __restrict__ sum, const float* __restrict__ sumsq,
                         const float* __restrict__ gamma, const float* __restrict__ beta,
                         float inv_n, int ch, size_t total) {
    size_t base = ((size_t)blockIdx.x * blockDim.x + threadIdx.x) * 8;
    if (base >= total) return;
    int c0 = (int)(base % (size_t)ch);
#pragma unroll
    for (int u = 0; u < 8; u++) {
        int c = c0 + u;
        float mean = sum[c] * inv_n;
        float var = sumsq[c] * inv_n - mean * mean;
        float rstd = rsqrtf(var + BNEPS);
        float v = ((float)X[base + u] - mean) * rstd * gamma[c] + beta[c];
        if (RELU) v = fmaxf(v, 0.f);
        out[base + u] = __float2bfloat16(v);
    }
}

// ---------------- Fused QKV GEMM: [32768,256] x 3x[256,256]^T ----------------
// q,k stored [n,h,s,d]; v stored transposed [n,h,d,s]
__global__ __launch_bounds__(256) void gemm_qkv(
    const bf16* __restrict__ hbuf, const bf16* __restrict__ Wq,
    const bf16* __restrict__ Wk, const bf16* __restrict__ Wv,
    bf16* __restrict__ qb, bf16* __restrict__ kb, bf16* __restrict__ vtb) {
    int m0 = blockIdx.x * 64;
    int by = blockIdx.y;            // 0..11
    int mat = by >> 2;              // 0=q 1=k 2=v
    int n0 = (by & 3) * 64;
    const bf16* B = (mat == 0) ? Wq : ((mat == 1) ? Wk : Wv);
    int lane = threadIdx.x & 63, wave = threadIdx.x >> 6;
    int quad = lane >> 4, l16 = lane & 15;
    int wm = (wave >> 1) * 32, wn = (wave & 1) * 32;
    f32x4 zero = {0.f, 0.f, 0.f, 0.f};
    f32x4 acc[2][2];
#pragma unroll
    for (int i = 0; i < 2; i++)
#pragma unroll
        for (int j = 0; j < 2; j++) acc[i][j] = zero;
    const int K = CC;
#pragma unroll
    for (int kk = 0; kk < K; kk += 32) {
        int kb_ = kk + quad * 8;
        bf16x8 a0 = ld8(hbuf + (size_t)(m0 + wm + l16) * K + kb_);
        bf16x8 a1 = ld8(hbuf + (size_t)(m0 + wm + 16 + l16) * K + kb_);
        bf16x8 b0 = ld8(B + (size_t)(n0 + wn + l16) * K + kb_);
        bf16x8 b1 = ld8(B + (size_t)(n0 + wn + 16 + l16) * K + kb_);
        acc[0][0] = __builtin_amdgcn_mfma_f32_16x16x32_bf16(a0, b0, acc[0][0], 0, 0, 0);
        acc[0][1] = __builtin_amdgcn_mfma_f32_16x16x32_bf16(a0, b1, acc[0][1], 0, 0, 0);
        acc[1][0] = __builtin_amdgcn_mfma_f32_16x16x32_bf16(a1, b0, acc[1][0], 0, 0, 0);
        acc[1][1] = __builtin_amdgcn_mfma_f32_16x16x32_bf16(a1, b1, acc[1][1], 0, 0, 0);
    }
#pragma unroll
    for (int i = 0; i < 2; i++)
#pragma unroll
        for (int j = 0; j < 2; j++)
#pragma unroll
            for (int r = 0; r < 4; r++) {
                int row = m0 + wm + i * 16 + quad * 4 + r;  // token
                int col = n0 + wn + j * 16 + l16;           // channel
                float v = acc[i][j][r];
                int n = row >> 7, s = row & 127, hh = col >> 5, jd = col & 31;
                if (mat < 2) {
                    bf16* dst = (mat == 0) ? qb : kb;
                    dst[(((size_t)(n * HH + hh)) * SS + s) * DD + jd] = __float2bfloat16(v);
                } else {
                    vtb[(((size_t)(n * HH + hh)) * DD + jd) * SS + s] = __float2bfloat16(v);
                }
            }
}

// ---------------- energy = Q K^T per (n,h): [128,32]x[128,32]^T ----------------
__global__ __launch_bounds__(256) void gemm_energy(const bf16* __restrict__ qb,
                                                   const bf16* __restrict__ kbuf,
                                                   bf16* __restrict__ E) {
    int nh = blockIdx.z;
    const bf16* A = qb + (size_t)nh * SS * DD;
    const bf16* B = kbuf + (size_t)nh * SS * DD;
    int m0 = blockIdx.x * 64, n0 = blockIdx.y * 64;
    int lane = threadIdx.x & 63, wave = threadIdx.x >> 6;
    int quad = lane >> 4, l16 = lane & 15;
    int wm = (wave >> 1) * 32, wn = (wave & 1) * 32;
    f32x4 zero = {0.f, 0.f, 0.f, 0.f};
    f32x4 acc[2][2];
#pragma unroll
    for (int i = 0; i < 2; i++)
#pragma unroll
        for (int j = 0; j < 2; j++) acc[i][j] = zero;
    int kb_ = quad * 8;  // K = 32, single step
    bf16x8 a0 = ld8(A + (size_t)(m0 + wm + l16) * DD + kb_);
    bf16x8 a1 = ld8(A + (size_t)(m0 + wm + 16 + l16) * DD + kb_);
    bf16x8 b0 = ld8(B + (size_t)(n0 + wn + l16) * DD + kb_);
    bf16x8 b1 = ld8(B + (size_t)(n0 + wn + 16 + l16) * DD + kb_);
    acc[0][0] = __builtin_amdgcn_mfma_f32_16x16x32_bf16(a0, b0, acc[0][0], 0, 0, 0);
    acc[0][1] = __builtin_amdgcn_mfma_f32_16x16x32_bf16(a0, b1, acc[0][1], 0, 0, 0);
    acc[1][0] = __builtin_amdgcn_mfma_f32_16x16x32_bf16(a1, b0, acc[1][0], 0, 0, 0);
    acc[1][1] = __builtin_amdgcn_mfma_f32_16x16x32_bf16(a1, b1, acc[1][1], 0, 0, 0);
    bf16* Eb = E + (size_t)nh * SS * SS;
#pragma unroll
    for (int i = 0; i < 2; i++)
#pragma unroll
        for (int j = 0; j < 2; j++)
#pragma unroll
            for (int r = 0; r < 4; r++) {
                int row = m0 + wm + i * 16 + quad * 4 + r;
                int col = n0 + wn + j * 16 + l16;
                Eb[(size_t)row * SS + col] = __float2bfloat16(acc[i][j][r]);
            }
}

// ---------------- BN(energy) + softmax + P V^T per (n,h) ----------------
__global__ __launch_bounds__(256) void att_kernel(
    const bf16* __restrict__ E, const bf16* __restrict__ vt,
    const float* __restrict__ pe_sum, const float* __restrict__ pe_sq,
    const float* __restrict__ g_pe, const float* __restrict__ b_pe,
    bf16* __restrict__ o) {
    __shared__ bf16 P[SS][136];  // +8 pad keeps b128 reads at <=2-way bank aliasing
    int nh = blockIdx.x;
    const bf16* Eb = E + (size_t)nh * SS * SS;
    int tid = threadIdx.x;
    const float inv_n = 1.0f / 2048.0f;
    // phase 1: affine-BN + 1/sqrt(C) scale -> LDS logits (bf16)
#pragma unroll
    for (int t = 0; t < 8; t++) {
        int e8 = (t * 256 + tid) * 8;
        bf16x8 ev = ld8(Eb + e8);
        int qi = e8 >> 7, ki = e8 & 127;
#pragma unroll
        for (int u = 0; u < 8; u++) {
            int chan = e8 + u;
            float mean = pe_sum[chan] * inv_n;
            float var = pe_sq[chan] * inv_n - mean * mean;
            float rstd = rsqrtf(var + BNEPS);
            float val = ((float)ev[u] - mean) * rstd * g_pe[chan] + b_pe[chan];
            P[qi][ki + u] = __float2bfloat16(val * 0.0625f);
        }
    }
    __syncthreads();
    // phase 2: softmax, one wave owns rows [wave*32, wave*32+32)
    int wave = tid >> 6, lane = tid & 63;
    for (int rr = 0; rr < 32; rr++) {
        int r = wave * 32 + rr;
        float x0 = (float)P[r][lane];
        float x1 = (float)P[r][lane + 64];
        float mx = fmaxf(x0, x1);
#pragma unroll
        for (int off = 32; off; off >>= 1) mx = fmaxf(mx, __shfl_xor(mx, off, 64));
        float e0 = __expf(x0 - mx), e1 = __expf(x1 - mx);
        float sm = e0 + e1;
#pragma unroll
        for (int off = 32; off; off >>= 1) sm += __shfl_xor(sm, off, 64);
        float inv = 1.0f / sm;
        P[r][lane] = __float2bfloat16(e0 * inv);
        P[r][lane + 64] = __float2bfloat16(e1 * inv);
    }
    __syncthreads();
    // phase 3: O = P @ V^T  (wave covers rows wave*32..+31, all 32 d-cols)
    int quad = lane >> 4, l16 = lane & 15;
    const bf16* V = vt + (size_t)nh * DD * SS;
    f32x4 zero = {0.f, 0.f, 0.f, 0.f};
    f32x4 acc[2][2];
#pragma unroll
    for (int i = 0; i < 2; i++)
#pragma unroll
        for (int j = 0; j < 2; j++) acc[i][j] = zero;
#pragma unroll
    for (int kk = 0; kk < SS; kk += 32) {
        int kb_ = kk + quad * 8;
        bf16x8 a0 = ld8(&P[wave * 32 + l16][kb_]);
        bf16x8 a1 = ld8(&P[wave * 32 + 16 + l16][kb_]);
        bf16x8 b0 = ld8(V + (size_t)(l16)*SS + kb_);
        bf16x8 b1 = ld8(V + (size_t)(16 + l16) * SS + kb_);
        acc[0][0] = __builtin_amdgcn_mfma_f32_16x16x32_bf16(a0, b0, acc[0][0], 0, 0, 0);
        acc[0][1] = __builtin_amdgcn_mfma_f32_16x16x32_bf16(a0, b1, acc[0][1], 0, 0, 0);
        acc[1][0] = __builtin_amdgcn_mfma_f32_16x16x32_bf16(a1, b0, acc[1][0], 0, 0, 0);
        acc[1][1] = __builtin_amdgcn_mfma_f32_16x16x32_bf16(a1, b1, acc[1][1], 0, 0, 0);
    }
    int nb = nh >> 3, hh = nh & 7;
#pragma unroll
    for (int i = 0; i < 2; i++)
#pragma unroll
        for (int j = 0; j < 2; j++)
#pragma unroll
            for (int r = 0; r < 4; r++) {
                int row_s = wave * 32 + i * 16 + quad * 4 + r;
                int jd = j * 16 + l16;
                int token = nb * SS + row_s;
                o[(size_t)token * CC + hh * DD + jd] = __float2bfloat16(acc[i][j][r]);
            }
}

// ---------------- Generic NT GEMM with epilogue modes ----------------
// MODE 0: out2 = A@B^T, store bf16
// MODE 1: x1 = A@B^T + bias + resf, store fp32
// MODE 2: out = A@B^T + resf, store fp32
template <int MODE>
__global__ __launch_bounds__(256) void gemm_nt(
    const bf16* __restrict__ A, const bf16* __restrict__ B, int N, int K,
    const float* __restrict__ bias, const float* __restrict__ resf,
    bf16* __restrict__ outb, float* __restrict__ outf) {
    int m0 = blockIdx.x * 64, n0 = blockIdx.y * 64;
    int lane = threadIdx.x & 63, wave = threadIdx.x >> 6;
    int quad = lane >> 4, l16 = lane & 15;
    int wm = (wave >> 1) * 32, wn = (wave & 1) * 32;
    f32x4 zero = {0.f, 0.f, 0.f, 0.f};
    f32x4 acc[2][2];
#pragma unroll
    for (int i = 0; i < 2; i++)
#pragma unroll
        for (int j = 0; j < 2; j++) acc[i][j] = zero;
    for (int kk = 0; kk < K; kk += 32) {
        int kb_ = kk + quad * 8;
        bf16x8 a0 = ld8(A + (size_t)(m0 + wm + l16) * K + kb_);
        bf16x8 a1 = ld8(A + (size_t)(m0 + wm + 16 + l16) * K + kb_);
        bf16x8 b0 = ld8(B + (size_t)(n0 + wn + l16) * K + kb_);
        bf16x8 b1 = ld8(B + (size_t)(n0 + wn + 16 + l16) * K + kb_);
        acc[0][0] = __builtin_amdgcn_mfma_f32_16x16x32_bf16(a0, b0, acc[0][0], 0, 0, 0);
        acc[0][1] = __builtin_amdgcn_mfma_f32_16x16x32_bf16(a0, b1, acc[0][1], 0, 0, 0);
        acc[1][0] = __builtin_amdgcn_mfma_f32_16x16x32_bf16(a1, b0, acc[1][0], 0, 0, 0);
        acc[1][1] = __builtin_amdgcn_mfma_f32_16x16x32_bf16(a1, b1, acc[1][1], 0, 0, 0);
    }
#pragma unroll
    for (int i = 0; i < 2; i++)
#pragma unroll
        for (int j = 0; j < 2; j++)
#pragma unroll
            for (int r = 0; r < 4; r++) {
                int row = m0 + wm + i * 16 + quad * 4 + r;
                int col = n0 + wn + j * 16 + l16;
                float v = acc[i][j][r];
                size_t idx = (size_t)row * N + col;
                if (MODE == 0) {
                    outb[idx] = __float2bfloat16(v);
                } else if (MODE == 1) {
                    outf[idx] = v + bias[col] + resf[idx];
                } else {
                    outf[idx] = v + resf[idx];
                }
            }
}

// ---------------- workspace layout (bytes) ----------------
#define WB_OFF 0u
#define HB_OFF 1048576u
#define Q_OFF 17825792u
#define K_OFF 34603008u
#define VT_OFF 51380224u
#define E_OFF 68157440u
#define O_OFF 1048576u      /* reuse hbuf */
#define X1_OFF 17825792u    /* fp32, over q+k */
#define OUT1_OFF 51380224u  /* over vt */
#define OUT2_OFF 68157440u  /* over E 1st half */
#define OUT4_OFF 101711872u /* over E 2nd half */
#define STATS_OFF 135266304u
#define STATS_FLOATS 34816u

extern "C" void kernel_launch(void* const* d_in, const int* in_sizes, int n_in,
                              void* d_out, int out_size, void* d_ws, size_t ws_size,
                              hipStream_t stream) {
    const float* x = (const float*)d_in[0];
    const float* g_n = (const float*)d_in[1];
    const float* b_n = (const float*)d_in[2];
    const float* Wq = (const float*)d_in[3];
    const float* Wk = (const float*)d_in[4];
    const float* Wv = (const float*)d_in[5];
    const float* Wo = (const float*)d_in[6];
    const float* bo = (const float*)d_in[7];
    const float* g_pe = (const float*)d_in[8];
    const float* b_pe = (const float*)d_in[9];
    const float* g0 = (const float*)d_in[10];
    const float* b0 = (const float*)d_in[11];
    const float* W0 = (const float*)d_in[12];
    const float* g1 = (const float*)d_in[13];
    const float* b1 = (const float*)d_in[14];
    const float* W1 = (const float*)d_in[15];

    char* ws = (char*)d_ws;
    bf16* WB = (bf16*)(ws + WB_OFF);
    bf16* WQB = WB;
    bf16* WKB = WB + 65536;
    bf16* WVB = WB + 131072;
    bf16* WOB = WB + 196608;
    bf16* W0B = WB + 262144;
    bf16* W1B = WB + 393216;
    bf16* hbuf = (bf16*)(ws + HB_OFF);
    bf16* qb = (bf16*)(ws + Q_OFF);
    bf16* kb = (bf16*)(ws + K_OFF);
    bf16* vtb = (bf16*)(ws + VT_OFF);
    bf16* Ebuf = (bf16*)(ws + E_OFF);
    bf16* obuf = (bf16*)(ws + O_OFF);
    float* x1 = (float*)(ws + X1_OFF);
    bf16* out1 = (bf16*)(ws + OUT1_OFF);
    bf16* out2 = (bf16*)(ws + OUT2_OFF);
    bf16* out4 = (bf16*)(ws + OUT4_OFF);
    float* stats = (float*)(ws + STATS_OFF);
    float* bn1_sum = stats;
    float* bn1_sq = stats + 256;
    float* pe_sum = stats + 512;
    float* pe_sq = stats + 512 + 16384;
    float* bn0_sum = stats + 33280;
    float* bn0_sq = stats + 33536;
    float* f1_sum = stats + 33792;
    float* f1_sq = stats + 34304;
    float* outp = (float*)d_out;

    hipMemsetAsync(ws + STATS_OFF, 0, STATS_FLOATS * 4, stream);

    // weights fp32 -> bf16
    cvt6<<<512, 256, 0, stream>>>(Wq, Wk, Wv, Wo, W0, W1, WB);
    // BN over x channels
    stats_kernel<float><<<dim3(1, 256), 256, 0, stream>>>(x, CC, 128, bn1_sum, bn1_sq);
    bn_apply<float, false><<<4096, 256, 0, stream>>>(x, hbuf, bn1_sum, bn1_sq, g_n, b_n,
                                                     1.0f / 32768.0f, CC, (size_t)NTOK * CC);
    // QKV
    gemm_qkv<<<dim3(512, 12), 256, 0, stream>>>(hbuf, WQB, WKB, WVB, qb, kb, vtb);
    // energy
    gemm_energy<<<dim3(2, 2, NHB), 256, 0, stream>>>(qb, kb, Ebuf);
    // BN stats over energy (channels = S*S, samples = m*H)
    stats_kernel<bf16><<<dim3(64, 16), 256, 0, stream>>>(Ebuf, SS * SS, 128, pe_sum, pe_sq);
    // BN + softmax + PV
    att_kernel<<<NHB, 256, 0, stream>>>(Ebuf, vtb, pe_sum, pe_sq, g_pe, b_pe, obuf);
    // x1 = o @ Wo^T + bo + x   (fp32)
    gemm_nt<1><<<dim3(512, 4), 256, 0, stream>>>(obuf, WOB, CC, CC, bo, x, nullptr, x1);
    // FFN
    stats_kernel<float><<<dim3(1, 256), 256, 0, stream>>>(x1, CC, 128, bn0_sum, bn0_sq);
    bn_apply<float, true><<<4096, 256, 0, stream>>>(x1, out1, bn0_sum, bn0_sq, g0, b0,
                                                    1.0f / 32768.0f, CC, (size_t)NTOK * CC);
    gemm_nt<0><<<dim3(512, 8), 256, 0, stream>>>(out1, W0B, 2 * CC, CC, nullptr, nullptr,
                                                 out2, nullptr);
    stats_kernel<bf16><<<dim3(2, 256), 256, 0, stream>>>(out2, 2 * CC, 128, f1_sum, f1_sq);
    bn_apply<bf16, true><<<8192, 256, 0, stream>>>(out2, out4, f1_sum, f1_sq, g1, b1,
                                                   1.0f / 32768.0f, 2 * CC, (size_t)NTOK * 2 * CC);
    gemm_nt<2><<<dim3(512, 4), 256, 0, stream>>>(out4, W1B, CC, 2 * CC, nullptr, x1,
                                                 nullptr, outp);
    (void)in_sizes; (void)n_in; (void)out_size; (void)ws_size;
}